// Round 13
// baseline (67.496 us; speedup 1.0000x reference)
//
#include <hip/hip_runtime.h>
#include <stdint.h>

typedef unsigned int u32;
typedef unsigned long long u64;

#define OCC_THR   0.5f
#define RADIUS_F  1.0f
#define D2_PRE    1.000002f   // d2 > this => sqrtf(d2) > 1.0f guaranteed
#define MAXP      8192
#define THREADS   512
#define TB        4           // trues per block -> 1024 blocks
#define PER       8           // true rows per thread in match (4096/512)
#define CAP       16          // per-true row capacity (P(>16) ~ 1e-18)
#define MAGIC     0x9E3779B9u

// ---------------- fused build + match, one non-cooperative dispatch --------
// Every block: zero-free block-private build of trues [bid*TB, +TB) sweeping
// all preds (R12-proven), rows SORTED in LDS before flush so all ws bytes are
// replay-deterministic; plain stores -> __threadfence() -> RELEASE flag
// (guide G16 cross-XCD pattern). Block 0 additionally ACQUIRE-spins on all
// flags (bounded), then runs the R12 deferred-acceptance match, then resets
// flags to 0 (no state relied on or left behind across calls).
__global__ void __launch_bounds__(THREADS) k_fused(
    const float4* __restrict__ pred, const float4* __restrict__ tru,
    int n_pred, int n_true, int nblocks,
    u32* __restrict__ counts, u64* __restrict__ crows,
    u32* __restrict__ gflags, float* __restrict__ out)
{
    __shared__ float4 st[TB];
    __shared__ u32    lcnt[TB];
    __shared__ u64    lrow[TB][CAP];
    __shared__ u32    s_owner[MAXP];   // 32 KB (match phase, block 0 only)
    __shared__ int    s_flag;
    __shared__ int    s_numtrue;
    __shared__ float  s_rd[8], s_rq[8];
    __shared__ int    s_rc[8];

    const int tid = threadIdx.x;
    const int bid = blockIdx.x;
    const int ti0 = bid * TB;

    // ---- build: block-private, zero-free ----
    if (tid < TB) {
        int i = ti0 + tid;
        st[tid]   = (i < n_true) ? tru[i] : make_float4(1e30f, 1e30f, 1e30f, 0.0f);
        lcnt[tid] = 0u;
    }
    __syncthreads();

    const float4 q0 = st[0], q1 = st[1], q2 = st[2], q3 = st[3];

#define TEST_T(t, q) {                                                       \
        float dx = (q).x - px, dy = (q).y - p.y, dz = (q).z - p.z;           \
        float d2 = dx*dx + dy*dy + dz*dz;                                    \
        if (d2 <= D2_PRE) {                                                  \
            float d = sqrtf(d2);                                             \
            if (d <= RADIUS_F) {      /* exact post-sqrt compare (ref) */    \
                u64 key = ((u64)__float_as_uint(d) << 32) | (u32)j;          \
                u32 slot = atomicAdd(&lcnt[t], 1u);                          \
                if (slot < (u32)CAP) lrow[t][slot] = key;                    \
            }                                                                \
        }                                                                    \
    }
    for (int j = tid; j < n_pred; j += THREADS) {
        const float4 p = pred[j];
        const float px = (p.w >= OCC_THR) ? p.x : 1e30f;   // cndmask, no branch
        TEST_T(0, q0) TEST_T(1, q1) TEST_T(2, q2) TEST_T(3, q3)
    }
#undef TEST_T
    __syncthreads();

    // ---- sort rows (deterministic ws bytes across replays) + flush ----
    if (tid < TB) {
        int i = ti0 + tid;
        if (i < n_true) {
            u32 c = lcnt[tid];
            if (c > (u32)CAP) c = (u32)CAP;
            for (u32 a = 1; a < c; ++a) {          // insertion sort, c ~ 1.35
                u64 v = lrow[tid][a];
                int b = (int)a - 1;
                while (b >= 0 && lrow[tid][b] > v) { lrow[tid][b+1] = lrow[tid][b]; --b; }
                lrow[tid][b+1] = v;
            }
            counts[i] = c;                          // unconditional
            for (u32 s = 0; s < c; ++s)
                crows[(size_t)i * CAP + s] = lrow[tid][s];
        }
    }
    __syncthreads();
    if (tid == 0) {
        __threadfence();                            // release all block stores
        __hip_atomic_store(&gflags[bid], MAGIC, __ATOMIC_RELEASE,
                           __HIP_MEMORY_SCOPE_AGENT);
    }

    if (bid != 0) return;

    // ---- block 0: wait for all producers (bounded acquire spin) ----
    for (int f = tid; f < nblocks; f += THREADS) {
        int guard = 0;
        while (__hip_atomic_load(&gflags[f], __ATOMIC_ACQUIRE,
                                 __HIP_MEMORY_SCOPE_AGENT) != MAGIC) {
            __builtin_amdgcn_s_sleep(2);
            if (++guard > 4000000) break;           // ~0.2 s safety, no hang
        }
    }
    __syncthreads();
    __threadfence();

    // ---- match: exact greedy via Gale-Shapley deferred acceptance ----
    // (R10/R11/R12-proven.) Round 1 proposes row[0] (sorted => row min);
    // rejected/evicted rescan their contiguous row with early exit.
    if (tid == 0) s_numtrue = 0;
    for (int j = tid; j < MAXP; j += THREADS) s_owner[j] = 0xFFFFFFFFu;

    float tp[PER]; u32 curj[PER]; float dist[PER]; u64 prop[PER];
    u64 pre[PER]; u32 eff[PER];
    u32 srch = 0;
    int myvalid = 0;

#define INIT_K(k) {                                                          \
        const int i = tid * PER + k;                                         \
        tp[k] = 0.0f; curj[k] = 0xFFFFFFFFu; dist[k] = 0.0f;                 \
        pre[k] = ~0ull; eff[k] = 0;                                          \
        if (i < n_true) {                                                    \
            float4 q = tru[i];                                               \
            tp[k] = q.w;                                                     \
            if (q.w >= OCC_THR) {                                            \
                myvalid++;                                                   \
                u32 c = counts[i];                                           \
                eff[k] = (c > (u32)CAP) ? (u32)CAP : c;                      \
                if (eff[k] > 0u) {                                           \
                    srch |= (1u << k);                                       \
                    pre[k] = crows[(size_t)i * CAP];  /* sorted row min */   \
                }                                                            \
            }                                                                \
        }                                                                    \
    }
    INIT_K(0) INIT_K(1) INIT_K(2) INIT_K(3)
    INIT_K(4) INIT_K(5) INIT_K(6) INIT_K(7)
#undef INIT_K

    if (myvalid) atomicAdd(&s_numtrue, myvalid);
    __syncthreads();

    for (;;) {
        if (tid == 0) s_flag = 0;
        __syncthreads();

#define PROP_K(k) {                                                          \
        prop[k] = ~0ull;                                                     \
        if (srch & (1u << k)) {                                              \
            const u32 i = (u32)(tid * PER + k);                              \
            u64 best;                                                        \
            if (pre[k] != ~0ull) { best = pre[k]; pre[k] = ~0ull; }          \
            else {                                                           \
                const u64* row = crows + (size_t)i * CAP;                    \
                best = ~0ull;                                                \
                for (u32 kk = 0; kk < eff[k]; ++kk) {                        \
                    u64 cd = row[kk];                                        \
                    if (s_owner[(u32)cd] > i) { best = cd; break; }          \
                }       /* sorted row: first available IS the min */         \
            }                                                                \
            if (best != ~0ull) {                                             \
                atomicMin(&s_owner[(u32)best], i);                           \
                prop[k] = best;                                              \
            } else {                                                         \
                srch &= ~(1u << k);   /* exhausted -> final unmatched */     \
            }                                                                \
        }                                                                    \
    }
        PROP_K(0) PROP_K(1) PROP_K(2) PROP_K(3)
        PROP_K(4) PROP_K(5) PROP_K(6) PROP_K(7)
#undef PROP_K
        __syncthreads();

        bool any = false;
#define ACC_K(k) {                                                           \
        const u32 i = (u32)(tid * PER + k);                                  \
        if (prop[k] != ~0ull) {                                              \
            const u32 j = (u32)prop[k];                                      \
            if (s_owner[j] == i) {        /* tentative hold */               \
                curj[k] = j;                                                 \
                dist[k] = __uint_as_float((u32)(prop[k] >> 32));             \
                srch &= ~(1u << k);                                          \
            } else { any = true; }        /* rejected -> retry */            \
        } else if (curj[k] != 0xFFFFFFFFu) {                                 \
            if (s_owner[curj[k]] != i) {  /* evicted by lower tag */         \
                curj[k] = 0xFFFFFFFFu;                                       \
                srch |= (1u << k);                                           \
                any = true;                                                  \
            }                                                                \
        }                                                                    \
    }
        ACC_K(0) ACC_K(1) ACC_K(2) ACC_K(3)
        ACC_K(4) ACC_K(5) ACC_K(6) ACC_K(7)
#undef ACC_K

        if (any) s_flag = 1;
        __syncthreads();
        if (!s_flag) break;
    }

    // ---- accumulate ----
    float sd = 0.0f, sq = 0.0f; int cnt = 0;
#define SUM_K(k) {                                                           \
        if (curj[k] != 0xFFFFFFFFu) {                                        \
            sd += dist[k];                                                   \
            float pw = pred[curj[k]].w;                                      \
            float df = tp[k] - pw;                                           \
            sq += df * df;                                                   \
            cnt++;                                                           \
        }                                                                    \
    }
    SUM_K(0) SUM_K(1) SUM_K(2) SUM_K(3)
    SUM_K(4) SUM_K(5) SUM_K(6) SUM_K(7)
#undef SUM_K

    for (int o = 32; o > 0; o >>= 1) {
        sd  += __shfl_down(sd,  o, 64);
        sq  += __shfl_down(sq,  o, 64);
        cnt += __shfl_down(cnt, o, 64);
    }
    const int wave = tid >> 6;
    if ((tid & 63) == 0) { s_rd[wave] = sd; s_rq[wave] = sq; s_rc[wave] = cnt; }
    __syncthreads();

    if (tid == 0) {
        float tsd = 0.0f, tsq = 0.0f; int tc = 0;
        for (int w = 0; w < THREADS / 64; ++w) { tsd += s_rd[w]; tsq += s_rq[w]; tc += s_rc[w]; }
        float num_true  = (float)s_numtrue;
        float cnt_f     = (float)tc;
        float unmatched = num_true - cnt_f;
        float denom     = fmaxf(cnt_f, 1.0f);
        bool  has       = tc > 0;
        float spatial   = RADIUS_F * 10.0f * unmatched + (has ? tsd / denom : 0.0f);
        float prob      = unmatched + (has ? tsq / denom : 0.0f);
        out[0] = spatial + prob;
    }
    __syncthreads();

    // ---- reset flags: identical ws protocol state at every call boundary ----
    for (int f = tid; f < nblocks; f += THREADS)
        __hip_atomic_store(&gflags[f], 0u, __ATOMIC_RELAXED,
                           __HIP_MEMORY_SCOPE_AGENT);
}

// ---------------- launch ----------------
extern "C" void kernel_launch(void* const* d_in, const int* in_sizes, int n_in,
                              void* d_out, int out_size, void* d_ws, size_t ws_size,
                              hipStream_t stream) {
    const float4* pred = (const float4*)d_in[0];
    const float4* tru  = (const float4*)d_in[1];
    const int n_pred = in_sizes[0] / 4;
    const int n_true = in_sizes[1] / 4;

    const int nblocks = (n_true + TB - 1) / TB;

    // ws layout: counts [n_true u32] | crows [n_true*CAP u64] | flags [nblocks u32]
    size_t counts_bytes = (size_t)n_true * sizeof(u32);
    size_t off_crows = (counts_bytes + 255) & ~(size_t)255;
    size_t off_flags = (off_crows + (size_t)n_true * CAP * 8 + 255) & ~(size_t)255;

    u32* counts = (u32*)d_ws;
    u64* crows  = (u64*)((char*)d_ws + off_crows);
    u32* gflags = (u32*)((char*)d_ws + off_flags);

    k_fused<<<nblocks, THREADS, 0, stream>>>(pred, tru, n_pred, n_true, nblocks,
                                             counts, crows, gflags, (float*)d_out);
}

// Round 14
// 35.898 us; speedup vs baseline: 1.8802x; 1.8802x over previous
//
#include <hip/hip_runtime.h>
#include <stdint.h>

typedef unsigned int u32;
typedef unsigned long long u64;

#define OCC_THR   0.5f
#define RADIUS_F  1.0f
#define D2_PRE    1.000002f   // d2 > this => sqrtf(d2) > 1.0f guaranteed
#define MAXP      8192
#define BTHREADS  256
#define TB        4       // trues per build block -> 1024 blocks (4/CU)
#define K2_THREADS 512
#define PER       8       // true rows per thread in match (4096/512)
#define CAP       16      // per-true row capacity (P(>16) ~ 1e-18)

// ---------------- Kernel 1: zero-free block-private build ------------------
// Block b owns trues [b*TB,+TB) in registers, sweeps all preds (L2-resident,
// coalesced). Rows + counters in block-private LDS, flushed UNCONDITIONALLY
// (no zeroing dispatch, poison-safe). Rows are SORTED before flush (avg 1.35
// entries) so crows[i*CAP] is the row min -> match round 1 needs no separate
// rowmin array, and rescans early-exit. 1024 blocks = full occupancy
// (R10's 512 was the mistake); invalid preds neutralized via cndmask;
// sqrtf only behind the exact d2 prefilter.
__global__ void __launch_bounds__(BTHREADS) k_build(
    const float4* __restrict__ pred, const float4* __restrict__ tru,
    int n_pred, int n_true,
    u32* __restrict__ counts, u64* __restrict__ crows)
{
    __shared__ float4 st[TB];
    __shared__ u32    lcnt[TB];
    __shared__ u64    lrow[TB][CAP];

    const int tid = threadIdx.x;
    const int ti0 = blockIdx.x * TB;

    if (tid < TB) {
        int i = ti0 + tid;
        st[tid]   = (i < n_true) ? tru[i] : make_float4(1e30f, 1e30f, 1e30f, 0.0f);
        lcnt[tid] = 0u;
    }
    __syncthreads();

    const float4 q0 = st[0], q1 = st[1], q2 = st[2], q3 = st[3];

#define TEST_T(t, q) {                                                       \
        float dx = (q).x - px, dy = (q).y - p.y, dz = (q).z - p.z;           \
        float d2 = dx*dx + dy*dy + dz*dz;                                    \
        if (d2 <= D2_PRE) {                                                  \
            float d = sqrtf(d2);                                             \
            if (d <= RADIUS_F) {      /* exact post-sqrt compare (ref) */    \
                u64 key = ((u64)__float_as_uint(d) << 32) | (u32)j;          \
                u32 slot = atomicAdd(&lcnt[t], 1u);                          \
                if (slot < (u32)CAP) lrow[t][slot] = key;                    \
            }                                                                \
        }                                                                    \
    }
    for (int j = tid; j < n_pred; j += BTHREADS) {
        const float4 p = pred[j];
        const float px = (p.w >= OCC_THR) ? p.x : 1e30f;   // cndmask, no branch
        TEST_T(0, q0) TEST_T(1, q1) TEST_T(2, q2) TEST_T(3, q3)
    }
#undef TEST_T
    __syncthreads();

    if (tid < TB) {
        int i = ti0 + tid;
        if (i < n_true) {
            u32 c = lcnt[tid];
            if (c > (u32)CAP) c = (u32)CAP;
            for (u32 a = 1; a < c; ++a) {          // insertion sort, c ~ 1.35
                u64 v = lrow[tid][a];
                int b = (int)a - 1;
                while (b >= 0 && lrow[tid][b] > v) { lrow[tid][b+1] = lrow[tid][b]; --b; }
                lrow[tid][b+1] = v;
            }
            counts[i] = c;                          // unconditional
            for (u32 s = 0; s < c; ++s)
                crows[(size_t)i * CAP + s] = lrow[tid][s];
        }
    }
}

// ---------------- Kernel 2: exact greedy via deferred acceptance -----------
// (R10/R11/R12-proven.) Sequential greedy == unique stable matching under
// common pred-side order (true index); Gale-Shapley computes it order-
// independently: owner[j] = min tag holding j; availability monotone-
// shrinking => rescans exact. Round 1 proposes crows[i*CAP] (sorted row
// min); rejected/evicted rescan their contiguous SORTED row (early exit:
// first available is the min).
__global__ void __launch_bounds__(K2_THREADS) k_match(
    const float4* __restrict__ pred, const float4* __restrict__ tru,
    int n_true,
    const u32* __restrict__ counts,
    const u64* __restrict__ crows,
    float* __restrict__ out)
{
    __shared__ u32   s_owner[MAXP];   // 32 KB
    __shared__ int   s_flag;
    __shared__ int   s_numtrue;
    __shared__ float s_rd[8], s_rq[8];
    __shared__ int   s_rc[8];

    const int tid = threadIdx.x;
    if (tid == 0) s_numtrue = 0;
    for (int j = tid; j < MAXP; j += K2_THREADS) s_owner[j] = 0xFFFFFFFFu;

    float tp[PER]; u32 curj[PER]; float dist[PER]; u64 prop[PER];
    u64 pre[PER]; u32 eff[PER];
    u32 srch = 0;
    int myvalid = 0;

#define INIT_K(k) {                                                          \
        const int i = tid * PER + k;                                         \
        tp[k] = 0.0f; curj[k] = 0xFFFFFFFFu; dist[k] = 0.0f;                 \
        pre[k] = ~0ull; eff[k] = 0;                                          \
        if (i < n_true) {                                                    \
            float4 q = tru[i];                                               \
            tp[k] = q.w;                                                     \
            if (q.w >= OCC_THR) {                                            \
                myvalid++;                                                   \
                u32 c = counts[i];                                           \
                eff[k] = (c > (u32)CAP) ? (u32)CAP : c;                      \
                if (eff[k] > 0u) {                                           \
                    srch |= (1u << k);                                       \
                    pre[k] = crows[(size_t)i * CAP];  /* sorted row min */   \
                }                                                            \
            }                                                                \
        }                                                                    \
    }
    INIT_K(0) INIT_K(1) INIT_K(2) INIT_K(3)
    INIT_K(4) INIT_K(5) INIT_K(6) INIT_K(7)
#undef INIT_K

    if (myvalid) atomicAdd(&s_numtrue, myvalid);
    __syncthreads();

    for (;;) {
        if (tid == 0) s_flag = 0;
        __syncthreads();

#define PROP_K(k) {                                                          \
        prop[k] = ~0ull;                                                     \
        if (srch & (1u << k)) {                                              \
            const u32 i = (u32)(tid * PER + k);                              \
            u64 best;                                                        \
            if (pre[k] != ~0ull) { best = pre[k]; pre[k] = ~0ull; }          \
            else {                                                           \
                const u64* row = crows + (size_t)i * CAP;                    \
                best = ~0ull;                                                \
                for (u32 kk = 0; kk < eff[k]; ++kk) {                        \
                    u64 cd = row[kk];                                        \
                    if (s_owner[(u32)cd] > i) { best = cd; break; }          \
                }       /* sorted row: first available IS the min */         \
            }                                                                \
            if (best != ~0ull) {                                             \
                atomicMin(&s_owner[(u32)best], i);                           \
                prop[k] = best;                                              \
            } else {                                                         \
                srch &= ~(1u << k);   /* exhausted -> final unmatched */     \
            }                                                                \
        }                                                                    \
    }
        PROP_K(0) PROP_K(1) PROP_K(2) PROP_K(3)
        PROP_K(4) PROP_K(5) PROP_K(6) PROP_K(7)
#undef PROP_K
        __syncthreads();

        bool any = false;
#define ACC_K(k) {                                                           \
        const u32 i = (u32)(tid * PER + k);                                  \
        if (prop[k] != ~0ull) {                                              \
            const u32 j = (u32)prop[k];                                      \
            if (s_owner[j] == i) {        /* tentative hold */               \
                curj[k] = j;                                                 \
                dist[k] = __uint_as_float((u32)(prop[k] >> 32));             \
                srch &= ~(1u << k);                                          \
            } else { any = true; }        /* rejected -> retry */            \
        } else if (curj[k] != 0xFFFFFFFFu) {                                 \
            if (s_owner[curj[k]] != i) {  /* evicted by lower tag */         \
                curj[k] = 0xFFFFFFFFu;                                       \
                srch |= (1u << k);                                           \
                any = true;                                                  \
            }                                                                \
        }                                                                    \
    }
        ACC_K(0) ACC_K(1) ACC_K(2) ACC_K(3)
        ACC_K(4) ACC_K(5) ACC_K(6) ACC_K(7)
#undef ACC_K

        if (any) s_flag = 1;
        __syncthreads();
        if (!s_flag) break;
    }

    // ---- accumulate ----
    float sd = 0.0f, sq = 0.0f; int cnt = 0;
#define SUM_K(k) {                                                           \
        if (curj[k] != 0xFFFFFFFFu) {                                        \
            sd += dist[k];                                                   \
            float pw = pred[curj[k]].w;                                      \
            float df = tp[k] - pw;                                           \
            sq += df * df;                                                   \
            cnt++;                                                           \
        }                                                                    \
    }
    SUM_K(0) SUM_K(1) SUM_K(2) SUM_K(3)
    SUM_K(4) SUM_K(5) SUM_K(6) SUM_K(7)
#undef SUM_K

    for (int o = 32; o > 0; o >>= 1) {
        sd  += __shfl_down(sd,  o, 64);
        sq  += __shfl_down(sq,  o, 64);
        cnt += __shfl_down(cnt, o, 64);
    }
    const int wave = tid >> 6;
    if ((tid & 63) == 0) { s_rd[wave] = sd; s_rq[wave] = sq; s_rc[wave] = cnt; }
    __syncthreads();

    if (tid == 0) {
        float tsd = 0.0f, tsq = 0.0f; int tc = 0;
        for (int w = 0; w < K2_THREADS / 64; ++w) { tsd += s_rd[w]; tsq += s_rq[w]; tc += s_rc[w]; }
        float num_true  = (float)s_numtrue;
        float cnt_f     = (float)tc;
        float unmatched = num_true - cnt_f;
        float denom     = fmaxf(cnt_f, 1.0f);
        bool  has       = tc > 0;
        float spatial   = RADIUS_F * 10.0f * unmatched + (has ? tsd / denom : 0.0f);
        float prob      = unmatched + (has ? tsq / denom : 0.0f);
        out[0] = spatial + prob;
    }
}

// ---------------- launch ----------------
extern "C" void kernel_launch(void* const* d_in, const int* in_sizes, int n_in,
                              void* d_out, int out_size, void* d_ws, size_t ws_size,
                              hipStream_t stream) {
    const float4* pred = (const float4*)d_in[0];
    const float4* tru  = (const float4*)d_in[1];
    const int n_pred = in_sizes[0] / 4;
    const int n_true = in_sizes[1] / 4;

    // ws layout: counts [n_true u32] | crows [n_true*CAP u64]
    size_t counts_bytes = (size_t)n_true * sizeof(u32);
    size_t off_crows = (counts_bytes + 255) & ~(size_t)255;

    u32* counts = (u32*)d_ws;
    u64* crows  = (u64*)((char*)d_ws + off_crows);

    k_build<<<(n_true + TB - 1) / TB, BTHREADS, 0, stream>>>(
        pred, tru, n_pred, n_true, counts, crows);
    k_match<<<1, K2_THREADS, 0, stream>>>(
        pred, tru, n_true, counts, crows, (float*)d_out);
}